// Round 17
// baseline (243.449 us; speedup 1.0000x reference)
//
#include <hip/hip_runtime.h>

#define N_NODES 10000
#define N_EDGESN 160000
#define E_TOT   (N_EDGESN + N_NODES)   // 170000
#define C 128
#define H 8
#define G 16
#define LLAYERS 5
#define NUM_FEAT 14
#define DIM_OUT 16
#define CH 16   // C/H
#define CG 8    // C/G
#define X16STRIDE (6*C)      // x16 row stride, fp16 (6 layer slots)

typedef _Float16 half8 __attribute__((ext_vector_type(8)));
typedef _Float16 half2v __attribute__((ext_vector_type(2)));

// ---- lin1 (+ zero counts): x (n,14) @ w (14,128) + b, relu -> x16[:,0,:] ----
__global__ __launch_bounds__(256) void k_lin1(const float* __restrict__ x,
                                              const float* __restrict__ w,
                                              const float* __restrict__ b,
                                              _Float16* __restrict__ x16,
                                              int* __restrict__ counts) {
    __shared__ float sw[NUM_FEAT * C];
    __shared__ float sb[C];
    int tid = threadIdx.x;
    int gid = blockIdx.x * 256 + tid;
    if (gid < N_NODES) counts[gid] = 0;
    for (int i = tid; i < NUM_FEAT * C; i += 256) sw[i] = w[i];
    if (tid < C) sb[tid] = b[tid];
    __syncthreads();
    int node = blockIdx.x * 2 + tid / C;
    int c = tid & (C - 1);
    if (node >= N_NODES) return;
    const float* xr = x + node * NUM_FEAT;
    float acc = sb[c];
#pragma unroll
    for (int f = 0; f < NUM_FEAT; f++) acc += xr[f] * sw[f * C + c];
    acc = fmaxf(acc, 0.0f);
    x16[(size_t)node * X16STRIDE + c] = (_Float16)acc;
}

// ---- degree count over original edges (by col); counts EXCLUDES self loop ----
__global__ void k_count(const int* __restrict__ col, int* __restrict__ counts) {
    int e = blockIdx.x * blockDim.x + threadIdx.x;
    if (e < N_EDGESN) atomicAdd(&counts[col[e]], 1);
}

// ---- single-block scan: (counts+1) -> offsets/cursor, dis, degree histogram
//      + DESCENDING bucket offsets (parallel reversed scan) ----
__global__ __launch_bounds__(1024) void k_scan(const int* __restrict__ counts,
                                               int* __restrict__ offs, int* __restrict__ cursor,
                                               float* __restrict__ dis,
                                               int* __restrict__ bucket_cur) {
    __shared__ int part[1024];
    __shared__ int hist[256];
    __shared__ int rs[256];
    const int CHK = (N_NODES + 1023) / 1024;   // 10
    int t = threadIdx.x;
    if (t < 256) hist[t] = 0;
    __syncthreads();
    int base = t * CHK;
    int loc[CHK];
    int sum = 0;
#pragma unroll
    for (int i = 0; i < CHK; i++) {
        int idx = base + i;
        int v = (idx < N_NODES) ? (counts[idx] + 1) : 0;
        loc[i] = sum;
        sum += v;
        if (idx < N_NODES) atomicAdd(&hist[min(v, 255)], 1);
    }
    part[t] = sum;
    __syncthreads();
    for (int off = 1; off < 1024; off <<= 1) {
        int v = (t >= off) ? part[t - off] : 0;
        __syncthreads();
        part[t] += v;
        __syncthreads();
    }
    int prev = (t > 0) ? part[t - 1] : 0;
#pragma unroll
    for (int i = 0; i < CHK; i++) {
        int idx = base + i;
        if (idx < N_NODES) {
            int o = prev + loc[i];
            offs[idx] = o;
            cursor[idx] = o;
            dis[idx] = rsqrtf((float)(counts[idx] + 1));
        }
    }
    if (t == 1023) offs[N_NODES] = part[1023];
    // descending-degree exclusive offsets via reversed parallel scan
    if (t < 256) rs[t] = hist[255 - t];
    __syncthreads();
    for (int off = 1; off < 256; off <<= 1) {
        int v = (t < 256 && t >= off) ? rs[t - off] : 0;
        __syncthreads();
        if (t < 256) rs[t] += v;
        __syncthreads();
    }
    if (t < 256) bucket_cur[255 - t] = rs[t] - hist[255 - t];
}

// ---- scatter edges into dest-sorted CSR + build degree-sorted node perm ----
__global__ void k_scatter(const int* __restrict__ row, const int* __restrict__ col,
                          const float* __restrict__ dis, const int* __restrict__ counts,
                          int* __restrict__ cursor, int2* __restrict__ csr,
                          int* __restrict__ bucket_cur, int* __restrict__ perm) {
    int e = blockIdx.x * blockDim.x + threadIdx.x;
    if (e < N_NODES) {
        int deg = min(counts[e] + 1, 255);
        int pos = atomicAdd(&bucket_cur[deg], 1);
        perm[pos] = e;
    }
    if (e >= E_TOT) return;
    int r = (e < N_EDGESN) ? row[e] : (e - N_EDGESN);
    int c = (e < N_EDGESN) ? col[e] : (e - N_EDGESN);
    int pos = atomicAdd(&cursor[c], 1);
    int2 pay;
    pay.x = r;
    pay.y = __float_as_int(dis[r]);
    csr[pos] = pay;
}

// ---- fused attention layer (r16 structure): ONE WAVE PER NODE, 4 waves/block,
//      d = perm[blockIdx*4+w]. fp16 state, V-fold, 2-deep pipeline, per-lane
//      epilogue (no LDS). NL==LLAYERS fuses lin2 in-wave (butterfly reduce). ----
template <int NL>
__global__ __launch_bounds__(256) void k_attn_fly(const int* __restrict__ offs,
                                                  const int2* __restrict__ csr,
                                                  const float* __restrict__ dis,
                                                  const int* __restrict__ perm,
                                                  const float* __restrict__ Wq, const float* __restrict__ bq,
                                                  const float* __restrict__ Wk, const float* __restrict__ bk,
                                                  const float* __restrict__ Wv, const float* __restrict__ bv,
                                                  _Float16* __restrict__ x16,
                                                  const float* __restrict__ lin2_w,
                                                  const float* __restrict__ lin2_b,
                                                  float* __restrict__ outp) {
    const int l = NL - 1;
    int w = threadIdx.x >> 6;
    int lane = threadIdx.x & 63;
    int d = perm[blockIdx.x * 4 + w];    // grid*4 == N_NODES exactly
    int g = lane >> 2;       // channel group 0..15
    int j4 = lane & 3;       // edge slice within wave
    int c0 = 2 * lane;       // output channels c0, c0+1  (= 8g + 2*j4)
    int o0 = 2 * j4;

    float y8[8];
    float z = 0.f;
    if constexpr (NL > 1) {
        // ---- per-node precompute: q8 -> y8, z (x_d from fp16) ----
        half8 hq = *(const half8*)(x16 + (size_t)d * X16STRIDE + l * C + 8 * g);
        float xdv[8];
#pragma unroll
        for (int i = 0; i < 8; i++) xdv[i] = (float)hq[i];
        const float* bqg = bq + l * C + 8 * g;
        float4 qa = *(const float4*)bqg;
        float4 qb = *(const float4*)(bqg + 4);
        const float* wq = Wq + l * (G * CG * CG) + g * (CG * CG);
#pragma unroll
        for (int i = 0; i < 8; i++) {
            float4 ra = *(const float4*)(wq + i * CG);
            float4 rb = *(const float4*)(wq + i * CG + 4);
            qa.x += xdv[i] * ra.x; qa.y += xdv[i] * ra.y;
            qa.z += xdv[i] * ra.z; qa.w += xdv[i] * ra.w;
            qb.x += xdv[i] * rb.x; qb.y += xdv[i] * rb.y;
            qb.z += xdv[i] * rb.z; qb.w += xdv[i] * rb.w;
        }
        const float* wk = Wk + l * (G * CG * CG) + g * (CG * CG);
#pragma unroll
        for (int j = 0; j < 8; j++) {
            float4 ra = *(const float4*)(wk + j * CG);
            float4 rb = *(const float4*)(wk + j * CG + 4);
            y8[j] = qa.x * ra.x + qa.y * ra.y + qa.z * ra.z + qa.w * ra.w
                  + qb.x * rb.x + qb.y * rb.y + qb.z * rb.z + qb.w * rb.w;
        }
        const float* bkg = bk + l * C + 8 * g;
        float4 ba = *(const float4*)bkg;
        float4 bb = *(const float4*)(bkg + 4);
        z = qa.x * ba.x + qa.y * ba.y + qa.z * ba.z + qa.w * ba.w
          + qb.x * bb.x + qb.y * bb.y + qb.z * bb.z + qb.w * bb.w;
    }

    const float disd = dis[d];
    const int p0 = offs[d], p1 = offs[d + 1];
    const float scale = 0.25f;   // 1/sqrt(CH=16)
    float xacc[8] = {0.f, 0.f, 0.f, 0.f, 0.f, 0.f, 0.f, 0.f};
    float nsum = 0.f;

    if constexpr (NL == 1) {
        for (int p = p0 + j4; p < p1; p += 4) {
            int2 pay = csr[p];
            float nrm = disd * __int_as_float(pay.y);
            half8 hv = *(const half8*)(x16 + (size_t)pay.x * X16STRIDE + 8 * g);
#pragma unroll
            for (int i = 0; i < 8; i++) xacc[i] += nrm * (float)hv[i];
            nsum += nrm;
        }
    } else {
        auto consume = [&](int2 pay, const half8 (&buf)[NL]) {
            float nrm = disd * __int_as_float(pay.y);
            float xv[NL][8];
            float sc[NL];
#pragma unroll
            for (int t = 0; t < NL; t++) {
#pragma unroll
                for (int i = 0; i < 8; i++) xv[t][i] = (float)buf[t][i];
                float part = z;
#pragma unroll
                for (int i = 0; i < 8; i++) part += xv[t][i] * y8[i];
                part += __shfl_xor(part, 4);   // combine the head's two groups
                sc[t] = part * scale;
            }
            float mx = sc[0];
#pragma unroll
            for (int t = 1; t < NL; t++) mx = fmaxf(mx, sc[t]);
            float s = 0.f;
            float ex[8] = {0.f, 0.f, 0.f, 0.f, 0.f, 0.f, 0.f, 0.f};
#pragma unroll
            for (int t = 0; t < NL; t++) {
                float e = __expf(sc[t] - mx);
                s += e;
#pragma unroll
                for (int i = 0; i < 8; i++) ex[i] += e * xv[t][i];
            }
            float inv = nrm * __builtin_amdgcn_rcpf(s);
#pragma unroll
            for (int i = 0; i < 8; i++) xacc[i] += inv * ex[i];
            nsum += nrm;
        };

        int p = p0 + j4;
        if (p < p1) {
            int2 payA = csr[p];
            half8 bufA[NL];
            {
                const _Float16* xs = x16 + (size_t)payA.x * X16STRIDE + 8 * g;
#pragma unroll
                for (int t = 0; t < NL; t++) bufA[t] = *(const half8*)(xs + t * C);
            }
            int pn = p + 4;
            int2 payB = csr[(pn < p1) ? pn : p];   // safe prefetch
            for (; pn < p1; pn += 4) {
                half8 bufB[NL];
                const _Float16* xs = x16 + (size_t)payB.x * X16STRIDE + 8 * g;
#pragma unroll
                for (int t = 0; t < NL; t++) bufB[t] = *(const half8*)(xs + t * C);
                int pc = pn + 4;
                int2 payC = csr[(pc < p1) ? pc : p0];
                consume(payA, bufA);
                payA = payB;
                payB = payC;
#pragma unroll
                for (int t = 0; t < NL; t++) bufA[t] = bufB[t];
            }
            consume(payA, bufA);
        }
    }

    // fold the 4 j4-slices of each group (lane bits 0,1)
#pragma unroll
    for (int i = 0; i < 8; i++) {
        xacc[i] += __shfl_xor(xacc[i], 1);
        xacc[i] += __shfl_xor(xacc[i], 2);
    }
    nsum += __shfl_xor(nsum, 1);
    nsum += __shfl_xor(nsum, 2);

    // epilogue: a{0,1} = relu(Wv xacc + bv*nsum) for channels c0, c0+1
    const float* wv = Wv + l * (G * CG * CG) + g * (CG * CG);
    float a0 = bv[l * C + c0] * nsum;
    float a1 = bv[l * C + c0 + 1] * nsum;
#pragma unroll
    for (int i = 0; i < 8; i++) {
        a0 += xacc[i] * wv[i * CG + o0];
        a1 += xacc[i] * wv[i * CG + o0 + 1];
    }
    a0 = fmaxf(a0, 0.f);
    a1 = fmaxf(a1, 0.f);

    if constexpr (NL < LLAYERS) {
        half2v ho;
        ho[0] = (_Float16)a0;
        ho[1] = (_Float16)a1;
        *(half2v*)(x16 + (size_t)d * X16STRIDE + (l + 1) * C + c0) = ho;
    } else {
        // fused lin2: out[d][o] = sum_c a_c * w[c][o] + b[o], butterfly over 64
        // lanes, 8 outputs at a time (keeps epilogue VGPR low).
        const float* w0 = lin2_w + c0 * DIM_OUT;
#pragma unroll
        for (int hs = 0; hs < 2; hs++) {
            float p[8];
#pragma unroll
            for (int o = 0; o < 8; o++) {
                int oo = hs * 8 + o;
                p[o] = a0 * w0[oo] + a1 * w0[DIM_OUT + oo];
            }
#pragma unroll
            for (int st = 1; st < 64; st <<= 1) {
#pragma unroll
                for (int o = 0; o < 8; o++) p[o] += __shfl_xor(p[o], st);
            }
            if ((lane >> 3) == hs && lane < 16)
                outp[d * DIM_OUT + lane] = p[lane & 7] + lin2_b[lane];
        }
    }
}

extern "C" void kernel_launch(void* const* d_in, const int* in_sizes, int n_in,
                              void* d_out, int out_size, void* d_ws, size_t ws_size,
                              hipStream_t stream) {
    const float* x      = (const float*)d_in[0];
    const int*   edge   = (const int*)d_in[1];
    const int*   row    = edge;              // edge_index[0]
    const int*   col    = edge + N_EDGESN;   // edge_index[1]
    const float* lin1_w = (const float*)d_in[2];
    const float* lin1_b = (const float*)d_in[3];
    const float* Wq     = (const float*)d_in[4];
    const float* bq     = (const float*)d_in[5];
    const float* Wk     = (const float*)d_in[6];
    const float* bk     = (const float*)d_in[7];
    const float* Wv     = (const float*)d_in[8];
    const float* bv     = (const float*)d_in[9];
    const float* lin2_w = (const float*)d_in[10];
    const float* lin2_b = (const float*)d_in[11];
    float* outp = (float*)d_out;

    _Float16* x16   = (_Float16*)d_ws;                               // n*6*C fp16
    int2*     csr   = (int2*)(x16 + (size_t)N_NODES * X16STRIDE);    // E_TOT int2 (8B-aligned)
    float*    dis   = (float*)(csr + E_TOT);                         // n
    int*   counts = (int*)(dis + N_NODES);                  // n
    int*   offs   = counts + N_NODES;                       // n+1
    int*   cursor = offs + N_NODES + 1;                     // n
    int*   bucket_cur = cursor + N_NODES;                   // 256
    int*   perm   = bucket_cur + 256;                       // n

    k_lin1<<<N_NODES / 2, 256, 0, stream>>>(x, lin1_w, lin1_b, x16, counts);
    k_count<<<(N_EDGESN + 255) / 256, 256, 0, stream>>>(col, counts);
    k_scan<<<1, 1024, 0, stream>>>(counts, offs, cursor, dis, bucket_cur);
    k_scatter<<<(E_TOT + 255) / 256, 256, 0, stream>>>(row, col, dis, counts, cursor, csr, bucket_cur, perm);

    const int ablocks = N_NODES / 4;   // 2500 blocks x 4 waves, one wave per node
    for (int l = 0; l < LLAYERS; l++) {
        switch (l) {
            case 0: k_attn_fly<1><<<ablocks, 256, 0, stream>>>(offs, csr, dis, perm, Wq, bq, Wk, bk, Wv, bv, x16, lin2_w, lin2_b, outp); break;
            case 1: k_attn_fly<2><<<ablocks, 256, 0, stream>>>(offs, csr, dis, perm, Wq, bq, Wk, bk, Wv, bv, x16, lin2_w, lin2_b, outp); break;
            case 2: k_attn_fly<3><<<ablocks, 256, 0, stream>>>(offs, csr, dis, perm, Wq, bq, Wk, bk, Wv, bv, x16, lin2_w, lin2_b, outp); break;
            case 3: k_attn_fly<4><<<ablocks, 256, 0, stream>>>(offs, csr, dis, perm, Wq, bq, Wk, bk, Wv, bv, x16, lin2_w, lin2_b, outp); break;
            case 4: k_attn_fly<5><<<ablocks, 256, 0, stream>>>(offs, csr, dis, perm, Wq, bq, Wk, bk, Wv, bv, x16, lin2_w, lin2_b, outp); break;
        }
    }
}

// Round 18
// 240.333 us; speedup vs baseline: 1.0130x; 1.0130x over previous
//
#include <hip/hip_runtime.h>

#define N_NODES 10000
#define N_EDGESN 160000
#define E_TOT   (N_EDGESN + N_NODES)   // 170000
#define C 128
#define H 8
#define G 16
#define LLAYERS 5
#define NUM_FEAT 14
#define DIM_OUT 16
#define CH 16   // C/H
#define CG 8    // C/G
#define X16STRIDE (6*C)      // x16 row stride, fp16 (6 layer slots)

typedef _Float16 half8 __attribute__((ext_vector_type(8)));
typedef _Float16 half2v __attribute__((ext_vector_type(2)));

// ---- lin1 (+ zero counts): x (n,14) @ w (14,128) + b, relu -> x16[:,0,:] ----
__global__ __launch_bounds__(256) void k_lin1(const float* __restrict__ x,
                                              const float* __restrict__ w,
                                              const float* __restrict__ b,
                                              _Float16* __restrict__ x16,
                                              int* __restrict__ counts) {
    __shared__ float sw[NUM_FEAT * C];
    __shared__ float sb[C];
    int tid = threadIdx.x;
    int gid = blockIdx.x * 256 + tid;
    if (gid < N_NODES) counts[gid] = 0;
    for (int i = tid; i < NUM_FEAT * C; i += 256) sw[i] = w[i];
    if (tid < C) sb[tid] = b[tid];
    __syncthreads();
    int node = blockIdx.x * 2 + tid / C;
    int c = tid & (C - 1);
    if (node >= N_NODES) return;
    const float* xr = x + node * NUM_FEAT;
    float acc = sb[c];
#pragma unroll
    for (int f = 0; f < NUM_FEAT; f++) acc += xr[f] * sw[f * C + c];
    acc = fmaxf(acc, 0.0f);
    x16[(size_t)node * X16STRIDE + c] = (_Float16)acc;
}

// ---- degree count over original edges (by col); counts EXCLUDES self loop ----
__global__ void k_count(const int* __restrict__ col, int* __restrict__ counts) {
    int e = blockIdx.x * blockDim.x + threadIdx.x;
    if (e < N_EDGESN) atomicAdd(&counts[col[e]], 1);
}

// ---- single-block scan: (counts+1) -> offsets/cursor, dis, degree histogram
//      + DESCENDING bucket offsets (parallel reversed scan) ----
__global__ __launch_bounds__(1024) void k_scan(const int* __restrict__ counts,
                                               int* __restrict__ offs, int* __restrict__ cursor,
                                               float* __restrict__ dis,
                                               int* __restrict__ bucket_cur) {
    __shared__ int part[1024];
    __shared__ int hist[256];
    __shared__ int rs[256];
    const int CHK = (N_NODES + 1023) / 1024;   // 10
    int t = threadIdx.x;
    if (t < 256) hist[t] = 0;
    __syncthreads();
    int base = t * CHK;
    int loc[CHK];
    int sum = 0;
#pragma unroll
    for (int i = 0; i < CHK; i++) {
        int idx = base + i;
        int v = (idx < N_NODES) ? (counts[idx] + 1) : 0;
        loc[i] = sum;
        sum += v;
        if (idx < N_NODES) atomicAdd(&hist[min(v, 255)], 1);
    }
    part[t] = sum;
    __syncthreads();
    for (int off = 1; off < 1024; off <<= 1) {
        int v = (t >= off) ? part[t - off] : 0;
        __syncthreads();
        part[t] += v;
        __syncthreads();
    }
    int prev = (t > 0) ? part[t - 1] : 0;
#pragma unroll
    for (int i = 0; i < CHK; i++) {
        int idx = base + i;
        if (idx < N_NODES) {
            int o = prev + loc[i];
            offs[idx] = o;
            cursor[idx] = o;
            dis[idx] = rsqrtf((float)(counts[idx] + 1));
        }
    }
    if (t == 1023) offs[N_NODES] = part[1023];
    // descending-degree exclusive offsets via reversed parallel scan
    if (t < 256) rs[t] = hist[255 - t];
    __syncthreads();
    for (int off = 1; off < 256; off <<= 1) {
        int v = (t < 256 && t >= off) ? rs[t - off] : 0;
        __syncthreads();
        if (t < 256) rs[t] += v;
        __syncthreads();
    }
    if (t < 256) bucket_cur[255 - t] = rs[t] - hist[255 - t];
}

// ---- scatter edges into dest-sorted CSR + build degree-sorted node perm ----
__global__ void k_scatter(const int* __restrict__ row, const int* __restrict__ col,
                          const float* __restrict__ dis, const int* __restrict__ counts,
                          int* __restrict__ cursor, int2* __restrict__ csr,
                          int* __restrict__ bucket_cur, int* __restrict__ perm) {
    int e = blockIdx.x * blockDim.x + threadIdx.x;
    if (e < N_NODES) {
        int deg = min(counts[e] + 1, 255);
        int pos = atomicAdd(&bucket_cur[deg], 1);
        perm[pos] = e;
    }
    if (e >= E_TOT) return;
    int r = (e < N_EDGESN) ? row[e] : (e - N_EDGESN);
    int c = (e < N_EDGESN) ? col[e] : (e - N_EDGESN);
    int pos = atomicAdd(&cursor[c], 1);
    int2 pay;
    pay.x = r;
    pay.y = __float_as_int(dis[r]);
    csr[pos] = pay;
}

// ---- fused attention layer (r16 exact): ONE WAVE PER NODE, 4 waves/block,
//      d = perm[blockIdx*4+w] (degree-sorted). Lane = (group g, slice j4);
//      slice j4 walks edges p = p0+j4 stride 4. fp16 state, V-fold,
//      2-deep software pipeline, per-lane epilogue (no LDS). ----
template <int NL>
__global__ __launch_bounds__(256) void k_attn_fly(const int* __restrict__ offs,
                                                  const int2* __restrict__ csr,
                                                  const float* __restrict__ dis,
                                                  const int* __restrict__ perm,
                                                  const float* __restrict__ Wq, const float* __restrict__ bq,
                                                  const float* __restrict__ Wk, const float* __restrict__ bk,
                                                  const float* __restrict__ Wv, const float* __restrict__ bv,
                                                  _Float16* __restrict__ x16) {
    const int l = NL - 1;
    int w = threadIdx.x >> 6;
    int lane = threadIdx.x & 63;
    int d = perm[blockIdx.x * 4 + w];    // grid*4 == N_NODES exactly
    int g = lane >> 2;       // channel group 0..15
    int j4 = lane & 3;       // edge slice within wave
    int c0 = 2 * lane;       // output channels c0, c0+1  (= 8g + 2*j4)
    int o0 = 2 * j4;

    float y8[8];
    float z = 0.f;
    if constexpr (NL > 1) {
        // ---- per-node precompute: q8 -> y8, z (x_d from fp16) ----
        half8 hq = *(const half8*)(x16 + (size_t)d * X16STRIDE + l * C + 8 * g);
        float xdv[8];
#pragma unroll
        for (int i = 0; i < 8; i++) xdv[i] = (float)hq[i];
        const float* bqg = bq + l * C + 8 * g;
        float4 qa = *(const float4*)bqg;
        float4 qb = *(const float4*)(bqg + 4);
        const float* wq = Wq + l * (G * CG * CG) + g * (CG * CG);
#pragma unroll
        for (int i = 0; i < 8; i++) {
            float4 ra = *(const float4*)(wq + i * CG);
            float4 rb = *(const float4*)(wq + i * CG + 4);
            qa.x += xdv[i] * ra.x; qa.y += xdv[i] * ra.y;
            qa.z += xdv[i] * ra.z; qa.w += xdv[i] * ra.w;
            qb.x += xdv[i] * rb.x; qb.y += xdv[i] * rb.y;
            qb.z += xdv[i] * rb.z; qb.w += xdv[i] * rb.w;
        }
        const float* wk = Wk + l * (G * CG * CG) + g * (CG * CG);
#pragma unroll
        for (int j = 0; j < 8; j++) {
            float4 ra = *(const float4*)(wk + j * CG);
            float4 rb = *(const float4*)(wk + j * CG + 4);
            y8[j] = qa.x * ra.x + qa.y * ra.y + qa.z * ra.z + qa.w * ra.w
                  + qb.x * rb.x + qb.y * rb.y + qb.z * rb.z + qb.w * rb.w;
        }
        const float* bkg = bk + l * C + 8 * g;
        float4 ba = *(const float4*)bkg;
        float4 bb = *(const float4*)(bkg + 4);
        z = qa.x * ba.x + qa.y * ba.y + qa.z * ba.z + qa.w * ba.w
          + qb.x * bb.x + qb.y * bb.y + qb.z * bb.z + qb.w * bb.w;
    }

    const float disd = dis[d];
    const int p0 = offs[d], p1 = offs[d + 1];
    const float scale = 0.25f;   // 1/sqrt(CH=16)
    float xacc[8] = {0.f, 0.f, 0.f, 0.f, 0.f, 0.f, 0.f, 0.f};
    float nsum = 0.f;

    if constexpr (NL == 1) {
        for (int p = p0 + j4; p < p1; p += 4) {
            int2 pay = csr[p];
            float nrm = disd * __int_as_float(pay.y);
            half8 hv = *(const half8*)(x16 + (size_t)pay.x * X16STRIDE + 8 * g);
#pragma unroll
            for (int i = 0; i < 8; i++) xacc[i] += nrm * (float)hv[i];
            nsum += nrm;
        }
    } else {
        auto consume = [&](int2 pay, const half8 (&buf)[NL]) {
            float nrm = disd * __int_as_float(pay.y);
            float xv[NL][8];
            float sc[NL];
#pragma unroll
            for (int t = 0; t < NL; t++) {
#pragma unroll
                for (int i = 0; i < 8; i++) xv[t][i] = (float)buf[t][i];
                float part = z;
#pragma unroll
                for (int i = 0; i < 8; i++) part += xv[t][i] * y8[i];
                part += __shfl_xor(part, 4);   // combine the head's two groups
                sc[t] = part * scale;
            }
            float mx = sc[0];
#pragma unroll
            for (int t = 1; t < NL; t++) mx = fmaxf(mx, sc[t]);
            float s = 0.f;
            float ex[8] = {0.f, 0.f, 0.f, 0.f, 0.f, 0.f, 0.f, 0.f};
#pragma unroll
            for (int t = 0; t < NL; t++) {
                float e = __expf(sc[t] - mx);
                s += e;
#pragma unroll
                for (int i = 0; i < 8; i++) ex[i] += e * xv[t][i];
            }
            float inv = nrm * __builtin_amdgcn_rcpf(s);
#pragma unroll
            for (int i = 0; i < 8; i++) xacc[i] += inv * ex[i];
            nsum += nrm;
        };

        int p = p0 + j4;
        if (p < p1) {
            int2 payA = csr[p];
            half8 bufA[NL];
            {
                const _Float16* xs = x16 + (size_t)payA.x * X16STRIDE + 8 * g;
#pragma unroll
                for (int t = 0; t < NL; t++) bufA[t] = *(const half8*)(xs + t * C);
            }
            int pn = p + 4;
            int2 payB = csr[(pn < p1) ? pn : p];   // safe prefetch
            for (; pn < p1; pn += 4) {
                half8 bufB[NL];
                const _Float16* xs = x16 + (size_t)payB.x * X16STRIDE + 8 * g;
#pragma unroll
                for (int t = 0; t < NL; t++) bufB[t] = *(const half8*)(xs + t * C);
                int pc = pn + 4;
                int2 payC = csr[(pc < p1) ? pc : p0];
                consume(payA, bufA);
                payA = payB;
                payB = payC;
#pragma unroll
                for (int t = 0; t < NL; t++) bufA[t] = bufB[t];
            }
            consume(payA, bufA);
        }
    }

    // fold the 4 j4-slices of each group (lane bits 0,1)
#pragma unroll
    for (int i = 0; i < 8; i++) {
        xacc[i] += __shfl_xor(xacc[i], 1);
        xacc[i] += __shfl_xor(xacc[i], 2);
    }
    nsum += __shfl_xor(nsum, 1);
    nsum += __shfl_xor(nsum, 2);

    // epilogue: out[c0,c0+1] = relu(Wv xacc + bv*nsum)
    const float* wv = Wv + l * (G * CG * CG) + g * (CG * CG);
    float a0 = bv[l * C + c0] * nsum;
    float a1 = bv[l * C + c0 + 1] * nsum;
#pragma unroll
    for (int i = 0; i < 8; i++) {
        a0 += xacc[i] * wv[i * CG + o0];
        a1 += xacc[i] * wv[i * CG + o0 + 1];
    }
    a0 = fmaxf(a0, 0.f);
    a1 = fmaxf(a1, 0.f);
    half2v ho;
    ho[0] = (_Float16)a0;
    ho[1] = (_Float16)a1;
    *(half2v*)(x16 + (size_t)d * X16STRIDE + (l + 1) * C + c0) = ho;
}

// ---- lin2: x16[:,5,:] (n,128) @ w (128,16) + b -> out ----
__global__ __launch_bounds__(256) void k_lin2(const _Float16* __restrict__ x16,
                                              const float* __restrict__ w,
                                              const float* __restrict__ b,
                                              float* __restrict__ out) {
    __shared__ float sw[C * DIM_OUT];
    __shared__ float sb[DIM_OUT];
    __shared__ float sx[16][C];
    int tid = threadIdx.x;
    for (int i = tid; i < C * DIM_OUT; i += 256) sw[i] = w[i];
    if (tid < DIM_OUT) sb[tid] = b[tid];
    int node0 = blockIdx.x * 16;
    {
        int nn = node0 + (tid >> 4);
        int co = (tid & 15) * 8;
        if (nn < N_NODES) {
            half8 hv = *(const half8*)(x16 + (size_t)nn * X16STRIDE + 5 * C + co);
#pragma unroll
            for (int i = 0; i < 8; i++) sx[tid >> 4][co + i] = (float)hv[i];
        } else {
#pragma unroll
            for (int i = 0; i < 8; i++) sx[tid >> 4][co + i] = 0.f;
        }
    }
    __syncthreads();
    int node = node0 + tid / DIM_OUT;
    int o = tid & (DIM_OUT - 1);
    if (node >= N_NODES) return;
    float acc = sb[o];
    const float* xr = sx[tid / DIM_OUT];
#pragma unroll 8
    for (int c = 0; c < C; c++) acc += xr[c] * sw[c * DIM_OUT + o];
    out[node * DIM_OUT + o] = acc;
}

extern "C" void kernel_launch(void* const* d_in, const int* in_sizes, int n_in,
                              void* d_out, int out_size, void* d_ws, size_t ws_size,
                              hipStream_t stream) {
    const float* x      = (const float*)d_in[0];
    const int*   edge   = (const int*)d_in[1];
    const int*   row    = edge;              // edge_index[0]
    const int*   col    = edge + N_EDGESN;   // edge_index[1]
    const float* lin1_w = (const float*)d_in[2];
    const float* lin1_b = (const float*)d_in[3];
    const float* Wq     = (const float*)d_in[4];
    const float* bq     = (const float*)d_in[5];
    const float* Wk     = (const float*)d_in[6];
    const float* bk     = (const float*)d_in[7];
    const float* Wv     = (const float*)d_in[8];
    const float* bv     = (const float*)d_in[9];
    const float* lin2_w = (const float*)d_in[10];
    const float* lin2_b = (const float*)d_in[11];
    float* outp = (float*)d_out;

    _Float16* x16   = (_Float16*)d_ws;                               // n*6*C fp16
    int2*     csr   = (int2*)(x16 + (size_t)N_NODES * X16STRIDE);    // E_TOT int2 (8B-aligned)
    float*    dis   = (float*)(csr + E_TOT);                         // n
    int*   counts = (int*)(dis + N_NODES);                  // n
    int*   offs   = counts + N_NODES;                       // n+1
    int*   cursor = offs + N_NODES + 1;                     // n
    int*   bucket_cur = cursor + N_NODES;                   // 256
    int*   perm   = bucket_cur + 256;                       // n

    k_lin1<<<N_NODES / 2, 256, 0, stream>>>(x, lin1_w, lin1_b, x16, counts);
    k_count<<<(N_EDGESN + 255) / 256, 256, 0, stream>>>(col, counts);
    k_scan<<<1, 1024, 0, stream>>>(counts, offs, cursor, dis, bucket_cur);
    k_scatter<<<(E_TOT + 255) / 256, 256, 0, stream>>>(row, col, dis, counts, cursor, csr, bucket_cur, perm);

    const int ablocks = N_NODES / 4;   // 2500 blocks x 4 waves, one wave per node
    for (int l = 0; l < LLAYERS; l++) {
        switch (l) {
            case 0: k_attn_fly<1><<<ablocks, 256, 0, stream>>>(offs, csr, dis, perm, Wq, bq, Wk, bk, Wv, bv, x16); break;
            case 1: k_attn_fly<2><<<ablocks, 256, 0, stream>>>(offs, csr, dis, perm, Wq, bq, Wk, bk, Wv, bv, x16); break;
            case 2: k_attn_fly<3><<<ablocks, 256, 0, stream>>>(offs, csr, dis, perm, Wq, bq, Wk, bk, Wv, bv, x16); break;
            case 3: k_attn_fly<4><<<ablocks, 256, 0, stream>>>(offs, csr, dis, perm, Wq, bq, Wk, bk, Wv, bv, x16); break;
            case 4: k_attn_fly<5><<<ablocks, 256, 0, stream>>>(offs, csr, dis, perm, Wq, bq, Wk, bk, Wv, bv, x16); break;
        }
    }
    k_lin2<<<(N_NODES + 15) / 16, 256, 0, stream>>>(x16, lin2_w, lin2_b, outp);
}